// Round 8
// baseline (460.052 us; speedup 1.0000x reference)
//
#include <hip/hip_runtime.h>

#define HW 4096
#define NC 256
#define NB 8
#define GN_EPS 1e-5f

typedef short bf16x8 __attribute__((ext_vector_type(8)));
typedef float f32x4 __attribute__((ext_vector_type(4)));
typedef float f32x16 __attribute__((ext_vector_type(16)));

#define MFMA16 __builtin_amdgcn_mfma_f32_16x16x32_bf16
#define MFMA32 __builtin_amdgcn_mfma_f32_32x32x16_bf16

// XOR swizzle for [row][64-col] bf16 LDS tiles (128B rows)
#define SWZ(row) ((((row) & 7) ^ (((row) >> 3) & 7)) << 4)

// q-scale folds 1/sqrt(256) AND log2(e) so softmax runs in base-2.
#define QSCALE 0.09016844f

__device__ __forceinline__ unsigned short f2bf(float f) {
  unsigned int u = __float_as_uint(f);
  u = (u + 0x7FFFu + ((u >> 16) & 1u)) >> 16;
  return (unsigned short)u;
}
__device__ __forceinline__ float bf2f(unsigned short h) {
  return __uint_as_float(((unsigned int)h) << 16);
}

__device__ __forceinline__ void gload16(const void* g, void* l) {
  __builtin_amdgcn_global_load_lds(
      (const __attribute__((address_space(1))) void*)g,
      (__attribute__((address_space(3))) void*)l, 16, 0, 0);
}

// ---------------------------------------------------------------- kernel 1
__global__ void gn_stats_kernel(const float* __restrict__ x,
                                const float* __restrict__ gnw,
                                const float* __restrict__ gnb,
                                float* __restrict__ s_arr,
                                float* __restrict__ t_arr) {
  int bg = blockIdx.x;
  int b = bg >> 5, g = bg & 31;
  const float4* base = (const float4*)(x + ((size_t)b * NC + g * 8) * HW);
  int tid = threadIdx.x;
  float s = 0.f, ss = 0.f;
  for (int it = 0; it < 32; ++it) {
    float4 v = base[tid + it * 256];
    s += v.x + v.y + v.z + v.w;
    ss += v.x * v.x + v.y * v.y + v.z * v.z + v.w * v.w;
  }
  for (int off = 32; off; off >>= 1) {
    s += __shfl_down(s, off);
    ss += __shfl_down(ss, off);
  }
  __shared__ float red[8];
  __shared__ float bc[2];
  int wave = tid >> 6, lane = tid & 63;
  if (lane == 0) { red[wave] = s; red[4 + wave] = ss; }
  __syncthreads();
  if (tid == 0) {
    float S = red[0] + red[1] + red[2] + red[3];
    float SS = red[4] + red[5] + red[6] + red[7];
    float mean = S * (1.f / 32768.f);
    float var = SS * (1.f / 32768.f) - mean * mean;
    bc[0] = mean;
    bc[1] = rsqrtf(var + GN_EPS);
  }
  __syncthreads();
  if (tid < 8) {
    int c = g * 8 + tid;
    float sv = bc[1] * gnw[c];
    s_arr[b * NC + c] = sv;
    t_arr[b * NC + c] = gnb[c] - bc[0] * sv;
  }
}

// ---------------------------------------------------------------- kernel 1b
__global__ void wconv_kernel(const float* __restrict__ qkvw,
                             const float* __restrict__ ow,
                             unsigned short* __restrict__ wb) {
  int i = blockIdx.x * 256 + threadIdx.x;  // 0..32767
  int off = i * 8;
  const float* src = (i < 24576) ? (qkvw + off) : (ow + (off - 196608));
  float4 a = *(const float4*)src;
  float4 c = *(const float4*)(src + 4);
  *(ushort4*)(wb + off) =
      make_ushort4(f2bf(a.x), f2bf(a.y), f2bf(a.z), f2bf(a.w));
  *(ushort4*)(wb + off + 4) =
      make_ushort4(f2bf(c.x), f2bf(c.y), f2bf(c.z), f2bf(c.w));
}

// ---------------------------------------------------------------- kernel 1c
__global__ __launch_bounds__(256) void gn_apply_kernel(
    const float* __restrict__ x, const float* __restrict__ s_arr,
    const float* __restrict__ t_arr, unsigned short* __restrict__ xt) {
  int b = blockIdx.z;
  int p0 = blockIdx.x * 64, c0 = blockIdx.y * 64;
  int tid = threadIdx.x;
  __shared__ unsigned short tl[64 * 64];  // [p][c] swizzled
  char* tB = (char*)tl;
  int cl = tid >> 4, p4 = tid & 15;
#pragma unroll
  for (int rep = 0; rep < 4; ++rep) {
    int c = cl + rep * 16;
    float4 xv = *(const float4*)(x + ((size_t)b * NC + c0 + c) * HW + p0 + p4 * 4);
    float sc = s_arr[b * NC + c0 + c];
    float tc = t_arr[b * NC + c0 + c];
    float vals[4] = {xv.x, xv.y, xv.z, xv.w};
#pragma unroll
    for (int i = 0; i < 4; ++i) {
      int p = p4 * 4 + i;
      *(unsigned short*)(tB + ((p * 128 + c * 2) ^ SWZ(p))) =
          f2bf(vals[i] * sc + tc);
    }
  }
  __syncthreads();
#pragma unroll
  for (int rep = 0; rep < 2; ++rep) {
    int p = (tid >> 3) + rep * 32;
    int c8 = (tid & 7) * 8;
    bf16x8 v = *(const bf16x8*)(tB + ((p * 128 + c8 * 2) ^ SWZ(p)));
    *(bf16x8*)(xt + ((size_t)b * HW + p0 + p) * NC + c0 + c8) = v;
  }
}

// ---------------------------------------------------------------- kernel 2
__global__ __launch_bounds__(256) void qkv_gemm_kernel(
    const unsigned short* __restrict__ xt, const unsigned short* __restrict__ wb,
    const float* __restrict__ bias, unsigned short* __restrict__ qb,
    unsigned short* __restrict__ kc_, unsigned short* __restrict__ vc) {
  int b = blockIdx.z;
  int p0 = blockIdx.x * 64;
  int o0 = blockIdx.y * 128;
  int tid = threadIdx.x;
  int wave = tid >> 6, lane = tid & 63;
  int l15 = lane & 15, q4 = lane >> 4;
  int wm = wave >> 1, wn = wave & 1;
  __shared__ unsigned short a_lds[2][64 * 64];   // [p][c] swizzled
  __shared__ unsigned short b_lds[2][128 * 64];  // [o][c] swizzled

  const char* xtb = (const char*)(xt + ((size_t)b * HW + p0) * NC);
  const char* wbb = (const char*)wb + o0 * 512;
  unsigned int asrc[2], bsrc[4];
#pragma unroll
  for (int i = 0; i < 2; ++i) {
    int dk = wave * 2048 + i * 1024 + lane * 16;
    int row = dk >> 7;
    asrc[i] = row * 512 + ((dk & 127) ^ SWZ(row));
  }
#pragma unroll
  for (int i = 0; i < 4; ++i) {
    int dk = wave * 4096 + i * 1024 + lane * 16;
    int row = dk >> 7;
    bsrc[i] = row * 512 + ((dk & 127) ^ SWZ(row));
  }

  f32x4 acc[2][4];
#pragma unroll
  for (int i = 0; i < 2; ++i)
#pragma unroll
    for (int j = 0; j < 4; ++j) acc[i][j] = (f32x4){0.f, 0.f, 0.f, 0.f};

#pragma unroll
  for (int i = 0; i < 2; ++i)
    gload16(xtb + asrc[i], (char*)a_lds[0] + wave * 2048 + i * 1024 + lane * 16);
#pragma unroll
  for (int i = 0; i < 4; ++i)
    gload16(wbb + bsrc[i], (char*)b_lds[0] + wave * 4096 + i * 1024 + lane * 16);
  __syncthreads();

  for (int kc = 0; kc < 4; ++kc) {
    int cur = kc & 1;
    if (kc < 3) {
      int koff = (kc + 1) * 128;
#pragma unroll
      for (int i = 0; i < 2; ++i)
        gload16(xtb + asrc[i] + koff,
                (char*)a_lds[cur ^ 1] + wave * 2048 + i * 1024 + lane * 16);
#pragma unroll
      for (int i = 0; i < 4; ++i)
        gload16(wbb + bsrc[i] + koff,
                (char*)b_lds[cur ^ 1] + wave * 4096 + i * 1024 + lane * 16);
    }
    const char* aB = (const char*)a_lds[cur];
    const char* bB = (const char*)b_lds[cur];
#pragma unroll
    for (int kk = 0; kk < 2; ++kk) {
      bf16x8 af[2], bfv[4];
#pragma unroll
      for (int pb = 0; pb < 2; ++pb) {
        int row = wm * 32 + pb * 16 + l15;
        af[pb] = *(const bf16x8*)(aB + ((row * 128 + kk * 64 + q4 * 16) ^ SWZ(row)));
      }
#pragma unroll
      for (int ob = 0; ob < 4; ++ob) {
        int row = wn * 64 + ob * 16 + l15;
        bfv[ob] = *(const bf16x8*)(bB + ((row * 128 + kk * 64 + q4 * 16) ^ SWZ(row)));
      }
#pragma unroll
      for (int pb = 0; pb < 2; ++pb)
#pragma unroll
        for (int ob = 0; ob < 4; ++ob)
          acc[pb][ob] = MFMA16(af[pb], bfv[ob], acc[pb][ob], 0, 0, 0);
    }
    __syncthreads();
  }

  for (int pb = 0; pb < 2; ++pb) {
    for (int ob = 0; ob < 4; ++ob) {
      int og = o0 + wn * 64 + ob * 16 + l15;
      int tsel = og >> 8, oc = og & 255;
      float bi = bias[og];
      if (tsel == 2) {
        int p = p0 + wm * 32 + pb * 16 + q4 * 4;
        ushort4 pk4 = make_ushort4(
            f2bf(acc[pb][ob][0] + bi), f2bf(acc[pb][ob][1] + bi),
            f2bf(acc[pb][ob][2] + bi), f2bf(acc[pb][ob][3] + bi));
        *(ushort4*)(vc + (((size_t)b * 512 + (p >> 3)) * 256 + oc) * 8 + (p & 7)) =
            pk4;
      } else {
        for (int r = 0; r < 4; ++r) {
          int p = p0 + wm * 32 + pb * 16 + q4 * 4 + r;
          float val = acc[pb][ob][r] + bi;
          if (tsel == 0) {
            qb[((size_t)b * HW + p) * NC + oc] = f2bf(val * QSCALE);
          } else {
            kc_[((size_t)(b * 32 + (oc >> 3)) * HW + p) * 8 + (oc & 7)] = f2bf(val);
          }
        }
      }
    }
  }
}

// ---------------------------------------------------------------- kernel 4
// Flash attention v7: 48KB LDS (K dbuf 2x16KB, V single 16KB) -> 3 blocks/CU.
// Per step: B1 -> issue K(t+1), V(t) -> QK(t) -> softmax/pack -> B2 (drains
// V(t),K(t+1)) -> PV(t). j split ns ways (starts int4); partials merged in
// outproj via L = m + log2(l).
__global__ __launch_bounds__(256, 3) void flash_attn_kernel(
    const unsigned short* __restrict__ qb, const unsigned short* __restrict__ kc_,
    const unsigned short* __restrict__ vc, unsigned short* __restrict__ Oh0,
    unsigned short* __restrict__ Oh1, unsigned short* __restrict__ Oh2,
    float* __restrict__ Lb, int4 starts) {
  int b = blockIdx.x & 7;           // batch -> XCD
  int qt = (blockIdx.x >> 3) & 31;  // q rows qt*128
  int js = blockIdx.x >> 8;         // j-split index
  int tid = threadIdx.x;
  int wave = tid >> 6, lane = tid & 63;
  int l31 = lane & 31;
  int hi = lane >> 5;

  int s0 = (js == 0) ? starts.x : (js == 1 ? starts.y : starts.z);
  int s1 = (js == 0) ? starts.y : (js == 1 ? starts.z : starts.w);
  int nt = s1 - s0;     // 42..64 tiles
  int j0b = s0 * 32;

  __shared__ unsigned short k_lds[2][8192];  // [buf][ch=32][j=32][e=8]
  __shared__ unsigned short v_lds[8192];     // [jc=4][c=256][e=8]

  const char* kp[4];
  const char* vp[4];
  {
    const char* kcb = (const char*)(kc_ + (size_t)b * 32 * HW * 8);
    const char* vcb = (const char*)(vc + (size_t)b * 512 * NC * 8);
#pragma unroll
    for (int i = 0; i < 4; ++i) {
      kp[i] = kcb + (size_t)((tid >> 5) + i * 8) * 65536 +
              (size_t)(j0b + (tid & 31)) * 16;
      vp[i] = vcb + (size_t)((j0b >> 3) + i) * 4096 + tid * 16;
    }
  }

  bf16x8 qf[16];
  {
    const unsigned short* qrow =
        qb + ((size_t)b * HW + qt * 128 + wave * 32 + l31) * NC;
#pragma unroll
    for (int kb = 0; kb < 16; ++kb)
      qf[kb] = *(const bf16x8*)(qrow + kb * 16 + hi * 8);
  }

  f32x16 acc[8];
#pragma unroll
  for (int nb = 0; nb < 8; ++nb)
#pragma unroll
    for (int i = 0; i < 16; ++i) acc[nb][i] = 0.f;
  float m_r = -1e30f, l_r = 0.f;

  // prologue: stage K(0) -> buf0 and V(0)
#pragma unroll
  for (int i = 0; i < 4; ++i)
    gload16(kp[i], (char*)k_lds[0] + tid * 16 + i * 4096);
#pragma unroll
  for (int i = 0; i < 4; ++i)
    gload16(vp[i], (char*)v_lds + tid * 16 + i * 4096);

  for (int t = 0; t < nt; ++t) {
    int cur = t & 1;
    __syncthreads();  // B1: t=0 drains prologue; t>0: all waves past PV(t-1)
    if (t < nt - 1) {  // stage K(t+1) into alt buffer
#pragma unroll
      for (int i = 0; i < 4; ++i) {
        kp[i] += 512;
        gload16(kp[i], (char*)k_lds[cur ^ 1] + tid * 16 + i * 4096);
      }
    }
    if (t >= 1) {  // stage V(t) into the single buffer (freed by B1)
#pragma unroll
      for (int i = 0; i < 4; ++i) {
        vp[i] += 16384;
        gload16(vp[i], (char*)v_lds + tid * 16 + i * 4096);
      }
    }
    const char* kB = (const char*)k_lds[cur];
    const char* vB = (const char*)v_lds;

    // S^T = K Q : lane holds S[j=(reg&3)+8*(reg>>2)+4*hi][q=l31]
    f32x16 p;
#pragma unroll
    for (int i = 0; i < 16; ++i) p[i] = 0.f;
    __builtin_amdgcn_s_setprio(1);
#pragma unroll
    for (int kb = 0; kb < 16; ++kb) {
      bf16x8 kf = *(const bf16x8*)(kB + (kb * 2 + hi) * 512 + l31 * 16);
      p = MFMA32(kf, qf[kb], p, 0, 0, 0);
    }
    __builtin_amdgcn_s_setprio(0);

    float pmax;
    {
      float t0 = fmaxf(p[0], p[1]), t1 = fmaxf(p[2], p[3]);
      float t2 = fmaxf(p[4], p[5]), t3 = fmaxf(p[6], p[7]);
      float t4 = fmaxf(p[8], p[9]), t5 = fmaxf(p[10], p[11]);
      float t6 = fmaxf(p[12], p[13]), t7 = fmaxf(p[14], p[15]);
      float u0 = fmaxf(t0, t1), u1 = fmaxf(t2, t3);
      float u2 = fmaxf(t4, t5), u3 = fmaxf(t6, t7);
      pmax = fmaxf(fmaxf(u0, u1), fmaxf(u2, u3));
    }
    pmax = fmaxf(pmax, __shfl_xor(pmax, 32));
    if (!__all(pmax - m_r <= 12.0f)) {
      float mn = fmaxf(m_r, pmax);
      float sf = exp2f(m_r - mn);
      m_r = mn;
      l_r *= sf;
#pragma unroll
      for (int reg = 0; reg < 16; ++reg) {
        float sfr = __shfl(sf, (reg & 3) + 8 * (reg >> 2) + 4 * hi);
#pragma unroll
        for (int nb = 0; nb < 8; ++nb) acc[nb][reg] *= sfr;
      }
    }
#pragma unroll
    for (int i = 0; i < 16; ++i) p[i] = __builtin_amdgcn_exp2f(p[i] - m_r);
    float rs;
    {
      float t0 = p[0] + p[1], t1 = p[2] + p[3];
      float t2 = p[4] + p[5], t3 = p[6] + p[7];
      float t4 = p[8] + p[9], t5 = p[10] + p[11];
      float t6 = p[12] + p[13], t7 = p[14] + p[15];
      float u0 = t0 + t1, u1 = t2 + t3, u2 = t4 + t5, u3 = t6 + t7;
      rs = (u0 + u1) + (u2 + u3);
    }
    rs += __shfl_xor(rs, 32);
    l_r += rs;

    int pk[8];
#pragma unroll
    for (int i = 0; i < 8; ++i) {
      int r;
      asm("v_cvt_pk_bf16_f32 %0, %1, %2"
          : "=v"(r)
          : "v"(p[2 * i]), "v"(p[2 * i + 1]));
      pk[i] = r;
    }
    union PU { int w[4]; bf16x8 v; } pu[2];
#pragma unroll
    for (int kb = 0; kb < 2; ++kb) {
      int base = 4 * kb;
      int pushA = hi ? pk[base + 0] : pk[base + 2];
      int pushB = hi ? pk[base + 1] : pk[base + 3];
      int shA = __shfl_xor(pushA, 32);
      int shB = __shfl_xor(pushB, 32);
      pu[kb].w[0] = hi ? shA : pk[base + 0];
      pu[kb].w[1] = hi ? shB : pk[base + 1];
      pu[kb].w[2] = hi ? pk[base + 2] : shA;
      pu[kb].w[3] = hi ? pk[base + 3] : shB;
    }

    __syncthreads();  // B2: V(t)+K(t+1) landed across all waves

    __builtin_amdgcn_s_setprio(1);
#pragma unroll
    for (int nb = 0; nb < 8; ++nb) {
#pragma unroll
      for (int kb = 0; kb < 2; ++kb) {
        bf16x8 vf = *(const bf16x8*)(vB + (kb * 2 + hi) * 4096 +
                                     (nb * 32 + l31) * 16);
        acc[nb] = MFMA32(pu[kb].v, vf, acc[nb], 0, 0, 0);
      }
    }
    __builtin_amdgcn_s_setprio(0);
  }

  float linv = 1.f / l_r;
  unsigned short* Ohp = (js == 0 ? Oh0 : (js == 1 ? Oh1 : Oh2)) +
                        ((size_t)b * HW + qt * 128 + wave * 32) * NC;
#pragma unroll
  for (int reg = 0; reg < 16; ++reg) {
    int row = (reg & 3) + 8 * (reg >> 2) + 4 * hi;
    float lr = __shfl(linv, row);
#pragma unroll
    for (int nb = 0; nb < 8; ++nb)
      Ohp[(size_t)row * NC + nb * 32 + l31] = f2bf(acc[nb][reg] * lr);
  }
  if (lane < 32) {
    float* Lp = Lb + (size_t)js * NB * HW;
    Lp[(size_t)b * HW + qt * 128 + wave * 32 + lane] = m_r + log2f(l_r);
  }
}

// ---------------------------------------------------------------- kernel 5
// out = out_w @ merged_att^T + out_b + x; ns-way partial-O merge in staging.
__global__ __launch_bounds__(256) void outproj_kernel(
    const unsigned short* __restrict__ owb, const float* __restrict__ obias,
    const unsigned short* __restrict__ Oh0, const unsigned short* __restrict__ Oh1,
    const unsigned short* __restrict__ Oh2, const float* __restrict__ Lb,
    const float* __restrict__ x, float* __restrict__ out, int ns) {
  int b = blockIdx.y;
  int p0 = blockIdx.x * 64;
  int tid = threadIdx.x;
  int wave = tid >> 6, lane = tid & 63;
  int l15 = lane & 15, q4 = lane >> 4;
  __shared__ unsigned short aw_lds[256 * 64];  // [o][c] swizzled
  __shared__ unsigned short bt_lds[64 * 64];   // [p][c] swizzled
  char* aB = (char*)aw_lds;
  char* bB = (char*)bt_lds;

  unsigned int wsrc[8];
#pragma unroll
  for (int i = 0; i < 8; ++i) {
    int dk = wave * 8192 + i * 1024 + lane * 16;
    int row = dk >> 7;
    wsrc[i] = row * 512 + ((dk & 127) ^ SWZ(row));
  }
  const char* owbb = (const char*)owb;

  f32x4 acc[4][4];
  for (int i = 0; i < 4; ++i)
    for (int j = 0; j < 4; ++j) acc[i][j] = (f32x4){0.f, 0.f, 0.f, 0.f};

  for (int kc0 = 0; kc0 < 256; kc0 += 64) {
    __syncthreads();
#pragma unroll
    for (int i = 0; i < 8; ++i)
      gload16(owbb + wsrc[i] + kc0 * 2,
              aB + wave * 8192 + i * 1024 + lane * 16);
    for (int it = 0; it < 2; ++it) {
      int idx = tid + it * 256;
      int p = idx >> 3, c8i = idx & 7;
      int row = p0 + p;
      float L0 = Lb[(size_t)b * HW + row];
      float L1 = Lb[(size_t)(NB + b) * HW + row];
      float L2 = (ns == 3) ? Lb[(size_t)(2 * NB + b) * HW + row] : -1e30f;
      float M = fmaxf(fmaxf(L0, L1), L2);
      float e0 = exp2f(L0 - M), e1 = exp2f(L1 - M);
      float e2 = (ns == 3) ? exp2f(L2 - M) : 0.f;
      float inv = 1.f / (e0 + e1 + e2);
      float w0 = e0 * inv, w1 = e1 * inv, w2 = e2 * inv;
      size_t ro = ((size_t)b * HW + row) * NC + kc0 + c8i * 8;
      uint4 ra = *(const uint4*)(Oh0 + ro);
      uint4 rb = *(const uint4*)(Oh1 + ro);
      uint4 rc = (ns == 3) ? *(const uint4*)(Oh2 + ro)
                           : make_uint4(0, 0, 0, 0);
      unsigned int aw[4] = {ra.x, ra.y, ra.z, ra.w};
      unsigned int bw[4] = {rb.x, rb.y, rb.z, rb.w};
      unsigned int cw[4] = {rc.x, rc.y, rc.z, rc.w};
      unsigned int outw[4];
      for (int i = 0; i < 4; ++i) {
        float lo = w0 * bf2f((unsigned short)(aw[i] & 0xffffu)) +
                   w1 * bf2f((unsigned short)(bw[i] & 0xffffu)) +
                   w2 * bf2f((unsigned short)(cw[i] & 0xffffu));
        float hic = w0 * bf2f((unsigned short)(aw[i] >> 16)) +
                    w1 * bf2f((unsigned short)(bw[i] >> 16)) +
                    w2 * bf2f((unsigned short)(cw[i] >> 16));
        int r;
        asm("v_cvt_pk_bf16_f32 %0, %1, %2" : "=v"(r) : "v"(lo), "v"(hic));
        outw[i] = (unsigned int)r;
      }
      *(uint4*)(bB + ((p * 128 + c8i * 16) ^ SWZ(p))) =
          make_uint4(outw[0], outw[1], outw[2], outw[3]);
    }
    __syncthreads();
#pragma unroll
    for (int kk = 0; kk < 2; ++kk) {
      bf16x8 af[4], bfv[4];
      for (int obk = 0; obk < 4; ++obk) {
        int row = wave * 64 + obk * 16 + l15;
        af[obk] = *(const bf16x8*)(aB + ((row * 128 + kk * 64 + q4 * 16) ^ SWZ(row)));
      }
      for (int pb = 0; pb < 4; ++pb) {
        int row = pb * 16 + l15;
        bfv[pb] = *(const bf16x8*)(bB + ((row * 128 + kk * 64 + q4 * 16) ^ SWZ(row)));
      }
      for (int obk = 0; obk < 4; ++obk)
        for (int pb = 0; pb < 4; ++pb)
          acc[obk][pb] = MFMA16(af[obk], bfv[pb], acc[obk][pb], 0, 0, 0);
    }
  }
  for (int obk = 0; obk < 4; ++obk)
    for (int pb = 0; pb < 4; ++pb)
      for (int r = 0; r < 4; ++r) {
        int o = wave * 64 + obk * 16 + q4 * 4 + r;
        int p = p0 + pb * 16 + l15;
        size_t gi = ((size_t)b * NC + o) * HW + p;
        out[gi] = acc[obk][pb][r] + obias[o] + x[gi];
      }
}

// ---------------------------------------------------------------- launch
extern "C" void kernel_launch(void* const* d_in, const int* in_sizes, int n_in,
                              void* d_out, int out_size, void* d_ws, size_t ws_size,
                              hipStream_t stream) {
  (void)in_sizes; (void)n_in; (void)out_size;
  const float* x = (const float*)d_in[0];
  const float* gnw = (const float*)d_in[1];
  const float* gnb = (const float*)d_in[2];
  const float* qkvw = (const float*)d_in[3];
  const float* qkvb = (const float*)d_in[4];
  const float* ow = (const float*)d_in[5];
  const float* obias = (const float*)d_in[6];
  float* out = (float*)d_out;

  char* ws = (char*)d_ws;
  float* s_arr = (float*)ws;
  float* t_arr = s_arr + NB * NC;
  size_t tsz = (size_t)NB * HW * NC;  // 8M ushort = 16MB

  // ns=3 layout needs 16384 + 6*tsz*2 + 384KB + 512KB ~ 97.5MB
  size_t need3 = 16384 + 6 * tsz * 2 + 3 * NB * HW * 4 + 262144 * 2;
  int ns = (ws_size >= need3) ? 3 : 2;

  unsigned short* qb = (unsigned short*)(ws + 16384);
  unsigned short* kc_ = qb + tsz;
  unsigned short* Oh0 = kc_ + tsz;
  unsigned short* vc = Oh0 + tsz;
  unsigned short* Oh1 = vc + tsz;
  unsigned short* Oh2 = (ns == 3) ? (Oh1 + tsz) : Oh1;  // dummy if ns==2
  float* Lb = (float*)(Oh2 + tsz);
  unsigned short* wb = (unsigned short*)(Lb + 3 * NB * HW);
  unsigned short* owb = wb + 196608;
  // xt aliases the last Oh partial (free until flash writes it)
  unsigned short* xt = (ns == 3) ? Oh2 : Oh1;
  if (ns == 2) Lb = (float*)(Oh1 + tsz);  // tighter layout for small ws
  if (ns == 2) { wb = (unsigned short*)(Lb + 3 * NB * HW); owb = wb + 196608; }

  int4 starts = (ns == 3) ? make_int4(0, 43, 86, 128) : make_int4(0, 64, 128, 128);

  hipLaunchKernelGGL(gn_stats_kernel, dim3(NB * 32), dim3(256), 0, stream,
                     x, gnw, gnb, s_arr, t_arr);
  hipLaunchKernelGGL(wconv_kernel, dim3(128), dim3(256), 0, stream,
                     qkvw, ow, wb);
  hipLaunchKernelGGL(gn_apply_kernel, dim3(64, 4, NB), dim3(256), 0, stream,
                     x, s_arr, t_arr, xt);
  hipLaunchKernelGGL(qkv_gemm_kernel, dim3(64, 6, NB), dim3(256), 0, stream,
                     xt, wb, qkvb, qb, kc_, vc);
  hipLaunchKernelGGL(flash_attn_kernel, dim3(256 * ns), dim3(256), 0, stream,
                     qb, kc_, vc, Oh0, Oh1, Oh2, Lb, starts);
  hipLaunchKernelGGL(outproj_kernel, dim3(64, NB), dim3(256), 0, stream,
                     owb, obias, Oh0, Oh1, Oh2, Lb, x, out, ns);
}

// Round 9
// 208.302 us; speedup vs baseline: 2.2086x; 2.2086x over previous
//
#include <hip/hip_runtime.h>

#define HW 4096
#define NC 256
#define NB 8
#define GN_EPS 1e-5f

typedef short bf16x8 __attribute__((ext_vector_type(8)));
typedef float f32x4 __attribute__((ext_vector_type(4)));
typedef float f32x16 __attribute__((ext_vector_type(16)));

#define MFMA16 __builtin_amdgcn_mfma_f32_16x16x32_bf16
#define MFMA32 __builtin_amdgcn_mfma_f32_32x32x16_bf16

// XOR swizzle for [row][64-col] bf16 LDS tiles (128B rows)
#define SWZ(row) ((((row) & 7) ^ (((row) >> 3) & 7)) << 4)

// q-scale folds 1/sqrt(256) AND log2(e) so softmax runs in base-2.
#define QSCALE 0.09016844f

__device__ __forceinline__ unsigned short f2bf(float f) {
  unsigned int u = __float_as_uint(f);
  u = (u + 0x7FFFu + ((u >> 16) & 1u)) >> 16;
  return (unsigned short)u;
}
__device__ __forceinline__ float bf2f(unsigned short h) {
  return __uint_as_float(((unsigned int)h) << 16);
}

__device__ __forceinline__ void gload16(const void* g, void* l) {
  __builtin_amdgcn_global_load_lds(
      (const __attribute__((address_space(1))) void*)g,
      (__attribute__((address_space(3))) void*)l, 16, 0, 0);
}

// cross-half (lane ^ 32) primitives via v_permlane32_swap_b32 (VALU-only,
// replaces ds_bpermute-based __shfl_xor(x,32)). After swap with d=s=x:
// d = {x.lo, x.lo}, s = {x.hi, x.hi}.
__device__ __forceinline__ float xhalf_max(float x) {
  float d = x, s = x;
  asm("v_permlane32_swap_b32 %0, %1" : "+v"(d), "+v"(s));
  return fmaxf(d, s);
}
__device__ __forceinline__ float xhalf_sum(float x) {
  float d = x, s = x;
  asm("v_permlane32_swap_b32 %0, %1" : "+v"(d), "+v"(s));
  return d + s;
}
__device__ __forceinline__ int xhalf_sel(int x, int hi) {
  int d = x, s = x;
  asm("v_permlane32_swap_b32 %0, %1" : "+v"(d), "+v"(s));
  return hi ? d : s;  // value from lane^32
}

// ---------------------------------------------------------------- kernel 1
__global__ void gn_stats_kernel(const float* __restrict__ x,
                                const float* __restrict__ gnw,
                                const float* __restrict__ gnb,
                                float* __restrict__ s_arr,
                                float* __restrict__ t_arr) {
  int bg = blockIdx.x;
  int b = bg >> 5, g = bg & 31;
  const float4* base = (const float4*)(x + ((size_t)b * NC + g * 8) * HW);
  int tid = threadIdx.x;
  float s = 0.f, ss = 0.f;
  for (int it = 0; it < 32; ++it) {
    float4 v = base[tid + it * 256];
    s += v.x + v.y + v.z + v.w;
    ss += v.x * v.x + v.y * v.y + v.z * v.z + v.w * v.w;
  }
  for (int off = 32; off; off >>= 1) {
    s += __shfl_down(s, off);
    ss += __shfl_down(ss, off);
  }
  __shared__ float red[8];
  __shared__ float bc[2];
  int wave = tid >> 6, lane = tid & 63;
  if (lane == 0) { red[wave] = s; red[4 + wave] = ss; }
  __syncthreads();
  if (tid == 0) {
    float S = red[0] + red[1] + red[2] + red[3];
    float SS = red[4] + red[5] + red[6] + red[7];
    float mean = S * (1.f / 32768.f);
    float var = SS * (1.f / 32768.f) - mean * mean;
    bc[0] = mean;
    bc[1] = rsqrtf(var + GN_EPS);
  }
  __syncthreads();
  if (tid < 8) {
    int c = g * 8 + tid;
    float sv = bc[1] * gnw[c];
    s_arr[b * NC + c] = sv;
    t_arr[b * NC + c] = gnb[c] - bc[0] * sv;
  }
}

// ---------------------------------------------------------------- kernel 1b
__global__ void wconv_kernel(const float* __restrict__ qkvw,
                             const float* __restrict__ ow,
                             unsigned short* __restrict__ wb) {
  int i = blockIdx.x * 256 + threadIdx.x;  // 0..32767
  int off = i * 8;
  const float* src = (i < 24576) ? (qkvw + off) : (ow + (off - 196608));
  float4 a = *(const float4*)src;
  float4 c = *(const float4*)(src + 4);
  *(ushort4*)(wb + off) =
      make_ushort4(f2bf(a.x), f2bf(a.y), f2bf(a.z), f2bf(a.w));
  *(ushort4*)(wb + off + 4) =
      make_ushort4(f2bf(c.x), f2bf(c.y), f2bf(c.z), f2bf(c.w));
}

// ---------------------------------------------------------------- kernel 1c
__global__ __launch_bounds__(256) void gn_apply_kernel(
    const float* __restrict__ x, const float* __restrict__ s_arr,
    const float* __restrict__ t_arr, unsigned short* __restrict__ xt) {
  int b = blockIdx.z;
  int p0 = blockIdx.x * 64, c0 = blockIdx.y * 64;
  int tid = threadIdx.x;
  __shared__ unsigned short tl[64 * 64];  // [p][c] swizzled
  char* tB = (char*)tl;
  int cl = tid >> 4, p4 = tid & 15;
#pragma unroll
  for (int rep = 0; rep < 4; ++rep) {
    int c = cl + rep * 16;
    float4 xv = *(const float4*)(x + ((size_t)b * NC + c0 + c) * HW + p0 + p4 * 4);
    float sc = s_arr[b * NC + c0 + c];
    float tc = t_arr[b * NC + c0 + c];
    float vals[4] = {xv.x, xv.y, xv.z, xv.w};
#pragma unroll
    for (int i = 0; i < 4; ++i) {
      int p = p4 * 4 + i;
      *(unsigned short*)(tB + ((p * 128 + c * 2) ^ SWZ(p))) =
          f2bf(vals[i] * sc + tc);
    }
  }
  __syncthreads();
#pragma unroll
  for (int rep = 0; rep < 2; ++rep) {
    int p = (tid >> 3) + rep * 32;
    int c8 = (tid & 7) * 8;
    bf16x8 v = *(const bf16x8*)(tB + ((p * 128 + c8 * 2) ^ SWZ(p)));
    *(bf16x8*)(xt + ((size_t)b * HW + p0 + p) * NC + c0 + c8) = v;
  }
}

// ---------------------------------------------------------------- kernel 2
__global__ __launch_bounds__(256) void qkv_gemm_kernel(
    const unsigned short* __restrict__ xt, const unsigned short* __restrict__ wb,
    const float* __restrict__ bias, unsigned short* __restrict__ qb,
    unsigned short* __restrict__ kc_, unsigned short* __restrict__ vc) {
  int b = blockIdx.z;
  int p0 = blockIdx.x * 64;
  int o0 = blockIdx.y * 128;
  int tid = threadIdx.x;
  int wave = tid >> 6, lane = tid & 63;
  int l15 = lane & 15, q4 = lane >> 4;
  int wm = wave >> 1, wn = wave & 1;
  __shared__ unsigned short a_lds[2][64 * 64];   // [p][c] swizzled
  __shared__ unsigned short b_lds[2][128 * 64];  // [o][c] swizzled

  const char* xtb = (const char*)(xt + ((size_t)b * HW + p0) * NC);
  const char* wbb = (const char*)wb + o0 * 512;
  unsigned int asrc[2], bsrc[4];
#pragma unroll
  for (int i = 0; i < 2; ++i) {
    int dk = wave * 2048 + i * 1024 + lane * 16;
    int row = dk >> 7;
    asrc[i] = row * 512 + ((dk & 127) ^ SWZ(row));
  }
#pragma unroll
  for (int i = 0; i < 4; ++i) {
    int dk = wave * 4096 + i * 1024 + lane * 16;
    int row = dk >> 7;
    bsrc[i] = row * 512 + ((dk & 127) ^ SWZ(row));
  }

  f32x4 acc[2][4];
#pragma unroll
  for (int i = 0; i < 2; ++i)
#pragma unroll
    for (int j = 0; j < 4; ++j) acc[i][j] = (f32x4){0.f, 0.f, 0.f, 0.f};

#pragma unroll
  for (int i = 0; i < 2; ++i)
    gload16(xtb + asrc[i], (char*)a_lds[0] + wave * 2048 + i * 1024 + lane * 16);
#pragma unroll
  for (int i = 0; i < 4; ++i)
    gload16(wbb + bsrc[i], (char*)b_lds[0] + wave * 4096 + i * 1024 + lane * 16);
  __syncthreads();

  for (int kc = 0; kc < 4; ++kc) {
    int cur = kc & 1;
    if (kc < 3) {
      int koff = (kc + 1) * 128;
#pragma unroll
      for (int i = 0; i < 2; ++i)
        gload16(xtb + asrc[i] + koff,
                (char*)a_lds[cur ^ 1] + wave * 2048 + i * 1024 + lane * 16);
#pragma unroll
      for (int i = 0; i < 4; ++i)
        gload16(wbb + bsrc[i] + koff,
                (char*)b_lds[cur ^ 1] + wave * 4096 + i * 1024 + lane * 16);
    }
    const char* aB = (const char*)a_lds[cur];
    const char* bB = (const char*)b_lds[cur];
#pragma unroll
    for (int kk = 0; kk < 2; ++kk) {
      bf16x8 af[2], bfv[4];
#pragma unroll
      for (int pb = 0; pb < 2; ++pb) {
        int row = wm * 32 + pb * 16 + l15;
        af[pb] = *(const bf16x8*)(aB + ((row * 128 + kk * 64 + q4 * 16) ^ SWZ(row)));
      }
#pragma unroll
      for (int ob = 0; ob < 4; ++ob) {
        int row = wn * 64 + ob * 16 + l15;
        bfv[ob] = *(const bf16x8*)(bB + ((row * 128 + kk * 64 + q4 * 16) ^ SWZ(row)));
      }
#pragma unroll
      for (int pb = 0; pb < 2; ++pb)
#pragma unroll
        for (int ob = 0; ob < 4; ++ob)
          acc[pb][ob] = MFMA16(af[pb], bfv[ob], acc[pb][ob], 0, 0, 0);
    }
    __syncthreads();
  }

  for (int pb = 0; pb < 2; ++pb) {
    for (int ob = 0; ob < 4; ++ob) {
      int og = o0 + wn * 64 + ob * 16 + l15;
      int tsel = og >> 8, oc = og & 255;
      float bi = bias[og];
      if (tsel == 2) {
        int p = p0 + wm * 32 + pb * 16 + q4 * 4;
        ushort4 pk4 = make_ushort4(
            f2bf(acc[pb][ob][0] + bi), f2bf(acc[pb][ob][1] + bi),
            f2bf(acc[pb][ob][2] + bi), f2bf(acc[pb][ob][3] + bi));
        *(ushort4*)(vc + (((size_t)b * 512 + (p >> 3)) * 256 + oc) * 8 + (p & 7)) =
            pk4;
      } else {
        for (int r = 0; r < 4; ++r) {
          int p = p0 + wm * 32 + pb * 16 + q4 * 4 + r;
          float val = acc[pb][ob][r] + bi;
          if (tsel == 0) {
            qb[((size_t)b * HW + p) * NC + oc] = f2bf(val * QSCALE);
          } else {
            kc_[((size_t)(b * 32 + (oc >> 3)) * HW + p) * 8 + (oc & 7)] = f2bf(val);
          }
        }
      }
    }
  }
}

// ---------------------------------------------------------------- kernel 4
// Flash attention v8: r7 structure (K/V both dbuf, 64KB LDS, 2 blocks/CU,
// 1 barrier/step) + QK split into two independent 8-MFMA chains + all
// cross-half shuffles via v_permlane32_swap (VALU-only).
__global__ __launch_bounds__(256, 2) void flash_attn_kernel(
    const unsigned short* __restrict__ qb, const unsigned short* __restrict__ kc_,
    const unsigned short* __restrict__ vc, unsigned short* __restrict__ Oh0,
    unsigned short* __restrict__ Oh1, float* __restrict__ Lb) {
  int b = blockIdx.x & 7;           // batch -> XCD
  int qt = (blockIdx.x >> 3) & 31;  // q rows qt*128
  int half = blockIdx.x >> 8;       // 0..1 (j halves)
  int tid = threadIdx.x;
  int wave = tid >> 6, lane = tid & 63;
  int l31 = lane & 31;
  int hi = lane >> 5;

  __shared__ unsigned short k_lds[2][8192];  // [buf][ch=32][j=32][e=8]
  __shared__ unsigned short v_lds[2][8192];  // [buf][jc=4][c=256][e=8]

  int j0b = half * 2048;

  const char* kp[4];
  const char* vp[4];
  {
    const char* kcb = (const char*)(kc_ + (size_t)b * 32 * HW * 8);
    const char* vcb = (const char*)(vc + (size_t)b * 512 * NC * 8);
#pragma unroll
    for (int i = 0; i < 4; ++i) {
      kp[i] = kcb + (size_t)((tid >> 5) + i * 8) * 65536 +
              (size_t)(j0b + (tid & 31)) * 16;
      vp[i] = vcb + (size_t)((j0b >> 3) + i) * 4096 + tid * 16;
    }
  }

  bf16x8 qf[16];
  {
    const unsigned short* qrow =
        qb + ((size_t)b * HW + qt * 128 + wave * 32 + l31) * NC;
#pragma unroll
    for (int kb = 0; kb < 16; ++kb)
      qf[kb] = *(const bf16x8*)(qrow + kb * 16 + hi * 8);
  }

  f32x16 acc[8];
#pragma unroll
  for (int nb = 0; nb < 8; ++nb)
#pragma unroll
    for (int i = 0; i < 16; ++i) acc[nb][i] = 0.f;
  float m_r = -1e30f, l_r = 0.f;

#pragma unroll
  for (int i = 0; i < 4; ++i)
    gload16(kp[i], (char*)k_lds[0] + tid * 16 + i * 4096);
#pragma unroll
  for (int i = 0; i < 4; ++i)
    gload16(vp[i], (char*)v_lds[0] + tid * 16 + i * 4096);
  __syncthreads();

  for (int t = 0; t < 64; ++t) {
    int cur = t & 1;
    if (t < 63) {
#pragma unroll
      for (int i = 0; i < 4; ++i) {
        kp[i] += 512;
        gload16(kp[i], (char*)k_lds[cur ^ 1] + tid * 16 + i * 4096);
      }
#pragma unroll
      for (int i = 0; i < 4; ++i) {
        vp[i] += 16384;
        gload16(vp[i], (char*)v_lds[cur ^ 1] + tid * 16 + i * 4096);
      }
    }
    const char* kB = (const char*)k_lds[cur];
    const char* vB = (const char*)v_lds[cur];

    // S^T = K Q as TWO independent 8-MFMA chains (halved dep latency)
    f32x16 pa_, pb_;
#pragma unroll
    for (int i = 0; i < 16; ++i) { pa_[i] = 0.f; pb_[i] = 0.f; }
    __builtin_amdgcn_s_setprio(1);
#pragma unroll
    for (int kb = 0; kb < 8; ++kb) {
      bf16x8 kf0 = *(const bf16x8*)(kB + (kb * 2 + hi) * 512 + l31 * 16);
      bf16x8 kf1 = *(const bf16x8*)(kB + ((kb + 8) * 2 + hi) * 512 + l31 * 16);
      pa_ = MFMA32(kf0, qf[kb], pa_, 0, 0, 0);
      pb_ = MFMA32(kf1, qf[kb + 8], pb_, 0, 0, 0);
    }
    __builtin_amdgcn_s_setprio(0);
    f32x16 p;
#pragma unroll
    for (int i = 0; i < 16; ++i) p[i] = pa_[i] + pb_[i];

    float pmax;
    {
      float t0 = fmaxf(p[0], p[1]), t1 = fmaxf(p[2], p[3]);
      float t2 = fmaxf(p[4], p[5]), t3 = fmaxf(p[6], p[7]);
      float t4 = fmaxf(p[8], p[9]), t5 = fmaxf(p[10], p[11]);
      float t6 = fmaxf(p[12], p[13]), t7 = fmaxf(p[14], p[15]);
      float u0 = fmaxf(t0, t1), u1 = fmaxf(t2, t3);
      float u2 = fmaxf(t4, t5), u3 = fmaxf(t6, t7);
      pmax = fmaxf(fmaxf(u0, u1), fmaxf(u2, u3));
    }
    pmax = xhalf_max(pmax);
    if (!__all(pmax - m_r <= 12.0f)) {
      float mn = fmaxf(m_r, pmax);
      float sf = exp2f(m_r - mn);
      m_r = mn;
      l_r *= sf;
#pragma unroll
      for (int reg = 0; reg < 16; ++reg) {
        float sfr = __shfl(sf, (reg & 3) + 8 * (reg >> 2) + 4 * hi);
#pragma unroll
        for (int nb = 0; nb < 8; ++nb) acc[nb][reg] *= sfr;
      }
    }
#pragma unroll
    for (int i = 0; i < 16; ++i) p[i] = __builtin_amdgcn_exp2f(p[i] - m_r);
    float rs;
    {
      float t0 = p[0] + p[1], t1 = p[2] + p[3];
      float t2 = p[4] + p[5], t3 = p[6] + p[7];
      float t4 = p[8] + p[9], t5 = p[10] + p[11];
      float t6 = p[12] + p[13], t7 = p[14] + p[15];
      float u0 = t0 + t1, u1 = t2 + t3, u2 = t4 + t5, u3 = t6 + t7;
      rs = (u0 + u1) + (u2 + u3);
    }
    l_r += xhalf_sum(rs);

    int pk[8];
#pragma unroll
    for (int i = 0; i < 8; ++i) {
      int r;
      asm("v_cvt_pk_bf16_f32 %0, %1, %2"
          : "=v"(r)
          : "v"(p[2 * i]), "v"(p[2 * i + 1]));
      pk[i] = r;
    }
    union PU { int w[4]; bf16x8 v; } pu[2];
#pragma unroll
    for (int kb = 0; kb < 2; ++kb) {
      int base = 4 * kb;
      int pushA = hi ? pk[base + 0] : pk[base + 2];
      int pushB = hi ? pk[base + 1] : pk[base + 3];
      int shA = xhalf_sel(pushA, hi);
      int shB = xhalf_sel(pushB, hi);
      pu[kb].w[0] = hi ? shA : pk[base + 0];
      pu[kb].w[1] = hi ? shB : pk[base + 1];
      pu[kb].w[2] = hi ? pk[base + 2] : shA;
      pu[kb].w[3] = hi ? pk[base + 3] : shB;
    }

    __builtin_amdgcn_s_setprio(1);
#pragma unroll
    for (int nb = 0; nb < 8; ++nb) {
#pragma unroll
      for (int kb = 0; kb < 2; ++kb) {
        bf16x8 vf = *(const bf16x8*)(vB + (kb * 2 + hi) * 4096 +
                                     (nb * 32 + l31) * 16);
        acc[nb] = MFMA32(pu[kb].v, vf, acc[nb], 0, 0, 0);
      }
    }
    __builtin_amdgcn_s_setprio(0);
    __syncthreads();
  }

  float linv = 1.f / l_r;
  unsigned short* Ohp = (half ? Oh1 : Oh0) +
                        ((size_t)b * HW + qt * 128 + wave * 32) * NC;
#pragma unroll
  for (int reg = 0; reg < 16; ++reg) {
    int row = (reg & 3) + 8 * (reg >> 2) + 4 * hi;
    float lr = __shfl(linv, row);
#pragma unroll
    for (int nb = 0; nb < 8; ++nb)
      Ohp[(size_t)row * NC + nb * 32 + l31] = f2bf(acc[nb][reg] * lr);
  }
  if (lane < 32) {
    float* Lp = Lb + (size_t)half * NB * HW;
    Lp[(size_t)b * HW + qt * 128 + wave * 32 + lane] = m_r + log2f(l_r);
  }
}

// ---------------------------------------------------------------- kernel 5
__global__ __launch_bounds__(256) void outproj_kernel(
    const unsigned short* __restrict__ owb, const float* __restrict__ obias,
    const unsigned short* __restrict__ Oh0, const unsigned short* __restrict__ Oh1,
    const float* __restrict__ Lb, const float* __restrict__ x,
    float* __restrict__ out) {
  int b = blockIdx.y;
  int p0 = blockIdx.x * 64;
  int tid = threadIdx.x;
  int wave = tid >> 6, lane = tid & 63;
  int l15 = lane & 15, q4 = lane >> 4;
  __shared__ unsigned short aw_lds[256 * 64];  // [o][c] swizzled
  __shared__ unsigned short bt_lds[64 * 64];   // [p][c] swizzled
  char* aB = (char*)aw_lds;
  char* bB = (char*)bt_lds;

  unsigned int wsrc[8];
#pragma unroll
  for (int i = 0; i < 8; ++i) {
    int dk = wave * 8192 + i * 1024 + lane * 16;
    int row = dk >> 7;
    wsrc[i] = row * 512 + ((dk & 127) ^ SWZ(row));
  }
  const char* owbb = (const char*)owb;

  f32x4 acc[4][4];
  for (int i = 0; i < 4; ++i)
    for (int j = 0; j < 4; ++j) acc[i][j] = (f32x4){0.f, 0.f, 0.f, 0.f};

  for (int kc0 = 0; kc0 < 256; kc0 += 64) {
    __syncthreads();
#pragma unroll
    for (int i = 0; i < 8; ++i)
      gload16(owbb + wsrc[i] + kc0 * 2,
              aB + wave * 8192 + i * 1024 + lane * 16);
    for (int it = 0; it < 2; ++it) {
      int idx = tid + it * 256;
      int p = idx >> 3, c8i = idx & 7;
      int row = p0 + p;
      float L1 = Lb[(size_t)b * HW + row];
      float L2 = Lb[(size_t)(NB + b) * HW + row];
      float w1 = 1.f / (1.f + exp2f(L2 - L1));
      float w2 = 1.f - w1;
      const unsigned short* o1p = Oh0 + ((size_t)b * HW + row) * NC + kc0 + c8i * 8;
      const unsigned short* o2p = Oh1 + ((size_t)b * HW + row) * NC + kc0 + c8i * 8;
      uint4 ra = *(const uint4*)o1p;
      uint4 rb = *(const uint4*)o2p;
      unsigned int aw[4] = {ra.x, ra.y, ra.z, ra.w};
      unsigned int bw[4] = {rb.x, rb.y, rb.z, rb.w};
      unsigned int outw[4];
      for (int i = 0; i < 4; ++i) {
        float lo = w1 * bf2f((unsigned short)(aw[i] & 0xffffu)) +
                   w2 * bf2f((unsigned short)(bw[i] & 0xffffu));
        float hic = w1 * bf2f((unsigned short)(aw[i] >> 16)) +
                    w2 * bf2f((unsigned short)(bw[i] >> 16));
        int r;
        asm("v_cvt_pk_bf16_f32 %0, %1, %2" : "=v"(r) : "v"(lo), "v"(hic));
        outw[i] = (unsigned int)r;
      }
      *(uint4*)(bB + ((p * 128 + c8i * 16) ^ SWZ(p))) =
          make_uint4(outw[0], outw[1], outw[2], outw[3]);
    }
    __syncthreads();
#pragma unroll
    for (int kk = 0; kk < 2; ++kk) {
      bf16x8 af[4], bfv[4];
      for (int obk = 0; obk < 4; ++obk) {
        int row = wave * 64 + obk * 16 + l15;
        af[obk] = *(const bf16x8*)(aB + ((row * 128 + kk * 64 + q4 * 16) ^ SWZ(row)));
      }
      for (int pb = 0; pb < 4; ++pb) {
        int row = pb * 16 + l15;
        bfv[pb] = *(const bf16x8*)(bB + ((row * 128 + kk * 64 + q4 * 16) ^ SWZ(row)));
      }
      for (int obk = 0; obk < 4; ++obk)
        for (int pb = 0; pb < 4; ++pb)
          acc[obk][pb] = MFMA16(af[obk], bfv[pb], acc[obk][pb], 0, 0, 0);
    }
  }
  for (int obk = 0; obk < 4; ++obk)
    for (int pb = 0; pb < 4; ++pb)
      for (int r = 0; r < 4; ++r) {
        int o = wave * 64 + obk * 16 + q4 * 4 + r;
        int p = p0 + pb * 16 + l15;
        size_t gi = ((size_t)b * NC + o) * HW + p;
        out[gi] = acc[obk][pb][r] + obias[o] + x[gi];
      }
}

// ---------------------------------------------------------------- launch
extern "C" void kernel_launch(void* const* d_in, const int* in_sizes, int n_in,
                              void* d_out, int out_size, void* d_ws, size_t ws_size,
                              hipStream_t stream) {
  (void)in_sizes; (void)n_in; (void)out_size; (void)ws_size;
  const float* x = (const float*)d_in[0];
  const float* gnw = (const float*)d_in[1];
  const float* gnb = (const float*)d_in[2];
  const float* qkvw = (const float*)d_in[3];
  const float* qkvb = (const float*)d_in[4];
  const float* ow = (const float*)d_in[5];
  const float* obias = (const float*)d_in[6];
  float* out = (float*)d_out;

  char* ws = (char*)d_ws;
  float* s_arr = (float*)ws;
  float* t_arr = s_arr + NB * NC;
  size_t tsz = (size_t)NB * HW * NC;  // 8M ushort = 16MB
  unsigned short* qb = (unsigned short*)(ws + 16384);
  unsigned short* kc_ = qb + tsz;
  unsigned short* Oh0 = kc_ + tsz;
  unsigned short* vc = Oh0 + tsz;
  unsigned short* Oh1 = vc + tsz;       // xt aliases this region pre-flash
  unsigned short* xt = Oh1;
  float* Lb = (float*)(Oh1 + tsz);      // 2*NB*HW f32 = 256KB
  unsigned short* wb = (unsigned short*)(Lb + 2 * NB * HW);  // 512KB bf16 W
  unsigned short* owb = wb + 196608;

  hipLaunchKernelGGL(gn_stats_kernel, dim3(NB * 32), dim3(256), 0, stream,
                     x, gnw, gnb, s_arr, t_arr);
  hipLaunchKernelGGL(wconv_kernel, dim3(128), dim3(256), 0, stream,
                     qkvw, ow, wb);
  hipLaunchKernelGGL(gn_apply_kernel, dim3(64, 4, NB), dim3(256), 0, stream,
                     x, s_arr, t_arr, xt);
  hipLaunchKernelGGL(qkv_gemm_kernel, dim3(64, 6, NB), dim3(256), 0, stream,
                     xt, wb, qkvb, qb, kc_, vc);
  hipLaunchKernelGGL(flash_attn_kernel, dim3(512), dim3(256), 0, stream,
                     qb, kc_, vc, Oh0, Oh1, Lb);
  hipLaunchKernelGGL(outproj_kernel, dim3(64, NB), dim3(256), 0, stream,
                     owb, obias, Oh0, Oh1, Lb, x, out);
}

// Round 11
// 207.838 us; speedup vs baseline: 2.2135x; 1.0022x over previous
//
#include <hip/hip_runtime.h>

#define HW 4096
#define NC 256
#define NB 8
#define GN_EPS 1e-5f

typedef short bf16x8 __attribute__((ext_vector_type(8)));
typedef float f32x4 __attribute__((ext_vector_type(4)));
typedef float f32x16 __attribute__((ext_vector_type(16)));

#define MFMA16 __builtin_amdgcn_mfma_f32_16x16x32_bf16
#define MFMA32 __builtin_amdgcn_mfma_f32_32x32x16_bf16

// XOR swizzle for [row][64-col] bf16 LDS tiles (128B rows)
#define SWZ(row) ((((row) & 7) ^ (((row) >> 3) & 7)) << 4)

// q-scale folds 1/sqrt(256) AND log2(e) so softmax runs in base-2.
#define QSCALE 0.09016844f

__device__ __forceinline__ unsigned short f2bf(float f) {
  unsigned int u = __float_as_uint(f);
  u = (u + 0x7FFFu + ((u >> 16) & 1u)) >> 16;
  return (unsigned short)u;
}
__device__ __forceinline__ float bf2f(unsigned short h) {
  return __uint_as_float(((unsigned int)h) << 16);
}

__device__ __forceinline__ void gload16(const void* g, void* l) {
  __builtin_amdgcn_global_load_lds(
      (const __attribute__((address_space(1))) void*)g,
      (__attribute__((address_space(3))) void*)l, 16, 0, 0);
}

// ---------------------------------------------------------------- kernel 1
__global__ void gn_stats_kernel(const float* __restrict__ x,
                                const float* __restrict__ gnw,
                                const float* __restrict__ gnb,
                                float* __restrict__ s_arr,
                                float* __restrict__ t_arr) {
  int bg = blockIdx.x;
  int b = bg >> 5, g = bg & 31;
  const float4* base = (const float4*)(x + ((size_t)b * NC + g * 8) * HW);
  int tid = threadIdx.x;
  float s = 0.f, ss = 0.f;
  for (int it = 0; it < 32; ++it) {
    float4 v = base[tid + it * 256];
    s += v.x + v.y + v.z + v.w;
    ss += v.x * v.x + v.y * v.y + v.z * v.z + v.w * v.w;
  }
  for (int off = 32; off; off >>= 1) {
    s += __shfl_down(s, off);
    ss += __shfl_down(ss, off);
  }
  __shared__ float red[8];
  __shared__ float bc[2];
  int wave = tid >> 6, lane = tid & 63;
  if (lane == 0) { red[wave] = s; red[4 + wave] = ss; }
  __syncthreads();
  if (tid == 0) {
    float S = red[0] + red[1] + red[2] + red[3];
    float SS = red[4] + red[5] + red[6] + red[7];
    float mean = S * (1.f / 32768.f);
    float var = SS * (1.f / 32768.f) - mean * mean;
    bc[0] = mean;
    bc[1] = rsqrtf(var + GN_EPS);
  }
  __syncthreads();
  if (tid < 8) {
    int c = g * 8 + tid;
    float sv = bc[1] * gnw[c];
    s_arr[b * NC + c] = sv;
    t_arr[b * NC + c] = gnb[c] - bc[0] * sv;
  }
}

// ---------------------------------------------------------------- kernel 1b
// Convert qkv_w (768x256) and out_w (256x256) fp32 -> bf16 into one buffer:
// wb[0..196607] = qkv_w, wb[196608..262143] = out_w.
__global__ void wconv_kernel(const float* __restrict__ qkvw,
                             const float* __restrict__ ow,
                             unsigned short* __restrict__ wb) {
  int i = blockIdx.x * 256 + threadIdx.x;  // 0..32767
  int off = i * 8;
  const float* src = (i < 24576) ? (qkvw + off) : (ow + (off - 196608));
  float4 a = *(const float4*)src;
  float4 c = *(const float4*)(src + 4);
  *(ushort4*)(wb + off) =
      make_ushort4(f2bf(a.x), f2bf(a.y), f2bf(a.z), f2bf(a.w));
  *(ushort4*)(wb + off + 4) =
      make_ushort4(f2bf(c.x), f2bf(c.y), f2bf(c.z), f2bf(c.w));
}

// ---------------------------------------------------------------- kernel 1c
// GN-apply + transpose + bf16: x[b][c][p] fp32 -> xt[b][p][c] bf16 (once).
__global__ __launch_bounds__(256) void gn_apply_kernel(
    const float* __restrict__ x, const float* __restrict__ s_arr,
    const float* __restrict__ t_arr, unsigned short* __restrict__ xt) {
  int b = blockIdx.z;
  int p0 = blockIdx.x * 64, c0 = blockIdx.y * 64;
  int tid = threadIdx.x;
  __shared__ unsigned short tl[64 * 64];  // [p][c] swizzled
  char* tB = (char*)tl;
  int cl = tid >> 4, p4 = tid & 15;
#pragma unroll
  for (int rep = 0; rep < 4; ++rep) {
    int c = cl + rep * 16;
    float4 xv = *(const float4*)(x + ((size_t)b * NC + c0 + c) * HW + p0 + p4 * 4);
    float sc = s_arr[b * NC + c0 + c];
    float tc = t_arr[b * NC + c0 + c];
    float vals[4] = {xv.x, xv.y, xv.z, xv.w};
#pragma unroll
    for (int i = 0; i < 4; ++i) {
      int p = p4 * 4 + i;
      *(unsigned short*)(tB + ((p * 128 + c * 2) ^ SWZ(p))) =
          f2bf(vals[i] * sc + tc);
    }
  }
  __syncthreads();
#pragma unroll
  for (int rep = 0; rep < 2; ++rep) {
    int p = (tid >> 3) + rep * 32;
    int c8 = (tid & 7) * 8;
    bf16x8 v = *(const bf16x8*)(tB + ((p * 128 + c8 * 2) ^ SWZ(p)));
    *(bf16x8*)(xt + ((size_t)b * HW + p0 + p) * NC + c0 + c8) = v;
  }
}

// ---------------------------------------------------------------- kernel 2
// QKV GEMM v2: A (xt) and B (wb, bf16) both staged via global_load_lds with
// pre-swizzled global sources; double-buffered K-chunks, 1 barrier/chunk.
// q -> qb[p][c] (scaled), k -> kc_[b][ch=c/8][p][e], v -> vc[b][jc=p/8][c][e].
__global__ __launch_bounds__(256) void qkv_gemm_kernel(
    const unsigned short* __restrict__ xt, const unsigned short* __restrict__ wb,
    const float* __restrict__ bias, unsigned short* __restrict__ qb,
    unsigned short* __restrict__ kc_, unsigned short* __restrict__ vc) {
  int b = blockIdx.z;
  int p0 = blockIdx.x * 64;
  int o0 = blockIdx.y * 128;
  int tid = threadIdx.x;
  int wave = tid >> 6, lane = tid & 63;
  int l15 = lane & 15, q4 = lane >> 4;
  int wm = wave >> 1, wn = wave & 1;
  __shared__ unsigned short a_lds[2][64 * 64];   // [p][c] swizzled
  __shared__ unsigned short b_lds[2][128 * 64];  // [o][c] swizzled

  const char* xtb = (const char*)(xt + ((size_t)b * HW + p0) * NC);
  const char* wbb = (const char*)wb + o0 * 512;
  unsigned int asrc[2], bsrc[4];
#pragma unroll
  for (int i = 0; i < 2; ++i) {
    int dk = wave * 2048 + i * 1024 + lane * 16;
    int row = dk >> 7;
    asrc[i] = row * 512 + ((dk & 127) ^ SWZ(row));
  }
#pragma unroll
  for (int i = 0; i < 4; ++i) {
    int dk = wave * 4096 + i * 1024 + lane * 16;
    int row = dk >> 7;
    bsrc[i] = row * 512 + ((dk & 127) ^ SWZ(row));
  }

  f32x4 acc[2][4];
#pragma unroll
  for (int i = 0; i < 2; ++i)
#pragma unroll
    for (int j = 0; j < 4; ++j) acc[i][j] = (f32x4){0.f, 0.f, 0.f, 0.f};

  // prologue: stage chunk 0
#pragma unroll
  for (int i = 0; i < 2; ++i)
    gload16(xtb + asrc[i], (char*)a_lds[0] + wave * 2048 + i * 1024 + lane * 16);
#pragma unroll
  for (int i = 0; i < 4; ++i)
    gload16(wbb + bsrc[i], (char*)b_lds[0] + wave * 4096 + i * 1024 + lane * 16);
  __syncthreads();

  for (int kc = 0; kc < 4; ++kc) {
    int cur = kc & 1;
    if (kc < 3) {
      int koff = (kc + 1) * 128;  // byte offset of next 64-c chunk
#pragma unroll
      for (int i = 0; i < 2; ++i)
        gload16(xtb + asrc[i] + koff,
                (char*)a_lds[cur ^ 1] + wave * 2048 + i * 1024 + lane * 16);
#pragma unroll
      for (int i = 0; i < 4; ++i)
        gload16(wbb + bsrc[i] + koff,
                (char*)b_lds[cur ^ 1] + wave * 4096 + i * 1024 + lane * 16);
    }
    const char* aB = (const char*)a_lds[cur];
    const char* bB = (const char*)b_lds[cur];
#pragma unroll
    for (int kk = 0; kk < 2; ++kk) {
      bf16x8 af[2], bfv[4];
#pragma unroll
      for (int pb = 0; pb < 2; ++pb) {
        int row = wm * 32 + pb * 16 + l15;
        af[pb] = *(const bf16x8*)(aB + ((row * 128 + kk * 64 + q4 * 16) ^ SWZ(row)));
      }
#pragma unroll
      for (int ob = 0; ob < 4; ++ob) {
        int row = wn * 64 + ob * 16 + l15;
        bfv[ob] = *(const bf16x8*)(bB + ((row * 128 + kk * 64 + q4 * 16) ^ SWZ(row)));
      }
#pragma unroll
      for (int pb = 0; pb < 2; ++pb)
#pragma unroll
        for (int ob = 0; ob < 4; ++ob)
          acc[pb][ob] = MFMA16(af[pb], bfv[ob], acc[pb][ob], 0, 0, 0);
    }
    __syncthreads();
  }

  for (int pb = 0; pb < 2; ++pb) {
    for (int ob = 0; ob < 4; ++ob) {
      int og = o0 + wn * 64 + ob * 16 + l15;
      int tsel = og >> 8, oc = og & 255;
      float bi = bias[og];
      if (tsel == 2) {  // V: 4 consecutive p share a chunk -> one ushort4 store
        int p = p0 + wm * 32 + pb * 16 + q4 * 4;
        ushort4 pk4 = make_ushort4(
            f2bf(acc[pb][ob][0] + bi), f2bf(acc[pb][ob][1] + bi),
            f2bf(acc[pb][ob][2] + bi), f2bf(acc[pb][ob][3] + bi));
        *(ushort4*)(vc + (((size_t)b * 512 + (p >> 3)) * 256 + oc) * 8 + (p & 7)) =
            pk4;
      } else {
        for (int r = 0; r < 4; ++r) {
          int p = p0 + wm * 32 + pb * 16 + q4 * 4 + r;
          float val = acc[pb][ob][r] + bi;
          if (tsel == 0) {
            qb[((size_t)b * HW + p) * NC + oc] = f2bf(val * QSCALE);
          } else {
            kc_[((size_t)(b * 32 + (oc >> 3)) * HW + p) * 8 + (oc & 7)] = f2bf(val);
          }
        }
      }
    }
  }
}

// ---------------------------------------------------------------- kernel 4
// Flash attention v6 (best verified: 153us, MfmaUtil 41%, 0 conflicts).
__global__ __launch_bounds__(256, 2) void flash_attn_kernel(
    const unsigned short* __restrict__ qb, const unsigned short* __restrict__ kc_,
    const unsigned short* __restrict__ vc, unsigned short* __restrict__ Oh0,
    unsigned short* __restrict__ Oh1, float* __restrict__ Lb) {
  int b = blockIdx.x & 7;           // batch -> XCD
  int qt = (blockIdx.x >> 3) & 31;  // q rows qt*128
  int half = blockIdx.x >> 8;       // 0..1 (j halves)
  int tid = threadIdx.x;
  int wave = tid >> 6, lane = tid & 63;
  int l31 = lane & 31;
  int hi = lane >> 5;

  __shared__ unsigned short k_lds[2][8192];  // [buf][ch=32][j=32][e=8]
  __shared__ unsigned short v_lds[2][8192];  // [buf][jc=4][c=256][e=8]

  int j0b = half * 2048;

  const char* kp[4];
  const char* vp[4];
  {
    const char* kcb = (const char*)(kc_ + (size_t)b * 32 * HW * 8);
    const char* vcb = (const char*)(vc + (size_t)b * 512 * NC * 8);
#pragma unroll
    for (int i = 0; i < 4; ++i) {
      kp[i] = kcb + (size_t)((tid >> 5) + i * 8) * 65536 +
              (size_t)(j0b + (tid & 31)) * 16;
      vp[i] = vcb + (size_t)((j0b >> 3) + i) * 4096 + tid * 16;
    }
  }

  bf16x8 qf[16];
  {
    const unsigned short* qrow =
        qb + ((size_t)b * HW + qt * 128 + wave * 32 + l31) * NC;
#pragma unroll
    for (int kb = 0; kb < 16; ++kb)
      qf[kb] = *(const bf16x8*)(qrow + kb * 16 + hi * 8);
  }

  f32x16 acc[8];
#pragma unroll
  for (int nb = 0; nb < 8; ++nb)
#pragma unroll
    for (int i = 0; i < 16; ++i) acc[nb][i] = 0.f;
  float m_r = -1e30f, l_r = 0.f;

#pragma unroll
  for (int i = 0; i < 4; ++i)
    gload16(kp[i], (char*)k_lds[0] + tid * 16 + i * 4096);
#pragma unroll
  for (int i = 0; i < 4; ++i)
    gload16(vp[i], (char*)v_lds[0] + tid * 16 + i * 4096);
  __syncthreads();

  for (int t = 0; t < 64; ++t) {
    int cur = t & 1;
    if (t < 63) {
#pragma unroll
      for (int i = 0; i < 4; ++i) {
        kp[i] += 512;
        gload16(kp[i], (char*)k_lds[cur ^ 1] + tid * 16 + i * 4096);
      }
#pragma unroll
      for (int i = 0; i < 4; ++i) {
        vp[i] += 16384;
        gload16(vp[i], (char*)v_lds[cur ^ 1] + tid * 16 + i * 4096);
      }
    }
    const char* kB = (const char*)k_lds[cur];
    const char* vB = (const char*)v_lds[cur];

    f32x16 p;
#pragma unroll
    for (int i = 0; i < 16; ++i) p[i] = 0.f;
    __builtin_amdgcn_s_setprio(1);
#pragma unroll
    for (int kb = 0; kb < 16; ++kb) {
      bf16x8 kf = *(const bf16x8*)(kB + (kb * 2 + hi) * 512 + l31 * 16);
      p = MFMA32(kf, qf[kb], p, 0, 0, 0);
    }
    __builtin_amdgcn_s_setprio(0);

    float pmax;
    {
      float t0 = fmaxf(p[0], p[1]), t1 = fmaxf(p[2], p[3]);
      float t2 = fmaxf(p[4], p[5]), t3 = fmaxf(p[6], p[7]);
      float t4 = fmaxf(p[8], p[9]), t5 = fmaxf(p[10], p[11]);
      float t6 = fmaxf(p[12], p[13]), t7 = fmaxf(p[14], p[15]);
      float u0 = fmaxf(t0, t1), u1 = fmaxf(t2, t3);
      float u2 = fmaxf(t4, t5), u3 = fmaxf(t6, t7);
      pmax = fmaxf(fmaxf(u0, u1), fmaxf(u2, u3));
    }
    pmax = fmaxf(pmax, __shfl_xor(pmax, 32));
    if (!__all(pmax - m_r <= 12.0f)) {
      float mn = fmaxf(m_r, pmax);
      float sf = exp2f(m_r - mn);
      m_r = mn;
      l_r *= sf;
#pragma unroll
      for (int reg = 0; reg < 16; ++reg) {
        float sfr = __shfl(sf, (reg & 3) + 8 * (reg >> 2) + 4 * hi);
#pragma unroll
        for (int nb = 0; nb < 8; ++nb) acc[nb][reg] *= sfr;
      }
    }
#pragma unroll
    for (int i = 0; i < 16; ++i) p[i] = __builtin_amdgcn_exp2f(p[i] - m_r);
    float rs;
    {
      float t0 = p[0] + p[1], t1 = p[2] + p[3];
      float t2 = p[4] + p[5], t3 = p[6] + p[7];
      float t4 = p[8] + p[9], t5 = p[10] + p[11];
      float t6 = p[12] + p[13], t7 = p[14] + p[15];
      float u0 = t0 + t1, u1 = t2 + t3, u2 = t4 + t5, u3 = t6 + t7;
      rs = (u0 + u1) + (u2 + u3);
    }
    rs += __shfl_xor(rs, 32);
    l_r += rs;

    int pk[8];
#pragma unroll
    for (int i = 0; i < 8; ++i) {
      int r;
      asm("v_cvt_pk_bf16_f32 %0, %1, %2"
          : "=v"(r)
          : "v"(p[2 * i]), "v"(p[2 * i + 1]));
      pk[i] = r;
    }
    union PU { int w[4]; bf16x8 v; } pu[2];
#pragma unroll
    for (int kb = 0; kb < 2; ++kb) {
      int base = 4 * kb;
      int pushA = hi ? pk[base + 0] : pk[base + 2];
      int pushB = hi ? pk[base + 1] : pk[base + 3];
      int shA = __shfl_xor(pushA, 32);
      int shB = __shfl_xor(pushB, 32);
      pu[kb].w[0] = hi ? shA : pk[base + 0];
      pu[kb].w[1] = hi ? shB : pk[base + 1];
      pu[kb].w[2] = hi ? pk[base + 2] : shA;
      pu[kb].w[3] = hi ? pk[base + 3] : shB;
    }

    __builtin_amdgcn_s_setprio(1);
#pragma unroll
    for (int nb = 0; nb < 8; ++nb) {
#pragma unroll
      for (int kb = 0; kb < 2; ++kb) {
        bf16x8 vf = *(const bf16x8*)(vB + (kb * 2 + hi) * 4096 +
                                     (nb * 32 + l31) * 16);
        acc[nb] = MFMA32(pu[kb].v, vf, acc[nb], 0, 0, 0);
      }
    }
    __builtin_amdgcn_s_setprio(0);
    __syncthreads();
  }

  float linv = 1.f / l_r;
  unsigned short* Ohp = (half ? Oh1 : Oh0) +
                        ((size_t)b * HW + qt * 128 + wave * 32) * NC;
#pragma unroll
  for (int reg = 0; reg < 16; ++reg) {
    int row = (reg & 3) + 8 * (reg >> 2) + 4 * hi;
    float lr = __shfl(linv, row);
#pragma unroll
    for (int nb = 0; nb < 8; ++nb)
      Ohp[(size_t)row * NC + nb * 32 + l31] = f2bf(acc[nb][reg] * lr);
  }
  if (lane < 32) {
    float* Lp = Lb + (size_t)half * NB * HW;
    Lp[(size_t)b * HW + qt * 128 + wave * 32 + lane] = m_r + log2f(l_r);
  }
}

// ---------------------------------------------------------------- kernel 5
// out = out_w @ merged_att^T + out_b + x. W staged async via global_load_lds
// (issued before the merge-VALU staging so the merge hides load latency).
__global__ __launch_bounds__(256) void outproj_kernel(
    const unsigned short* __restrict__ owb, const float* __restrict__ obias,
    const unsigned short* __restrict__ Oh0, const unsigned short* __restrict__ Oh1,
    const float* __restrict__ Lb, const float* __restrict__ x,
    float* __restrict__ out) {
  int b = blockIdx.y;
  int p0 = blockIdx.x * 64;
  int tid = threadIdx.x;
  int wave = tid >> 6, lane = tid & 63;
  int l15 = lane & 15, q4 = lane >> 4;
  __shared__ unsigned short aw_lds[256 * 64];  // [o][c] swizzled
  __shared__ unsigned short bt_lds[64 * 64];   // [p][c] swizzled
  char* aB = (char*)aw_lds;
  char* bB = (char*)bt_lds;

  unsigned int wsrc[8];
#pragma unroll
  for (int i = 0; i < 8; ++i) {
    int dk = wave * 8192 + i * 1024 + lane * 16;
    int row = dk >> 7;
    wsrc[i] = row * 512 + ((dk & 127) ^ SWZ(row));
  }
  const char* owbb = (const char*)owb;

  f32x4 acc[4][4];
  for (int i = 0; i < 4; ++i)
    for (int j = 0; j < 4; ++j) acc[i][j] = (f32x4){0.f, 0.f, 0.f, 0.f};

  for (int kc0 = 0; kc0 < 256; kc0 += 64) {
    __syncthreads();
    // issue W gloads first (async)
#pragma unroll
    for (int i = 0; i < 8; ++i)
      gload16(owbb + wsrc[i] + kc0 * 2,
              aB + wave * 8192 + i * 1024 + lane * 16);
    // merge-stage att tile (VALU work overlaps the W loads)
    for (int it = 0; it < 2; ++it) {
      int idx = tid + it * 256;
      int p = idx >> 3, c8i = idx & 7;
      int row = p0 + p;
      float L1 = Lb[(size_t)b * HW + row];
      float L2 = Lb[(size_t)(NB + b) * HW + row];
      float w1 = 1.f / (1.f + exp2f(L2 - L1));
      float w2 = 1.f - w1;
      const unsigned short* o1p = Oh0 + ((size_t)b * HW + row) * NC + kc0 + c8i * 8;
      const unsigned short* o2p = Oh1 + ((size_t)b * HW + row) * NC + kc0 + c8i * 8;
      uint4 ra = *(const uint4*)o1p;
      uint4 rb = *(const uint4*)o2p;
      unsigned int aw[4] = {ra.x, ra.y, ra.z, ra.w};
      unsigned int bw[4] = {rb.x, rb.y, rb.z, rb.w};
      unsigned int outw[4];
      for (int i = 0; i < 4; ++i) {
        float lo = w1 * bf2f((unsigned short)(aw[i] & 0xffffu)) +
                   w2 * bf2f((unsigned short)(bw[i] & 0xffffu));
        float hic = w1 * bf2f((unsigned short)(aw[i] >> 16)) +
                    w2 * bf2f((unsigned short)(bw[i] >> 16));
        int r;
        asm("v_cvt_pk_bf16_f32 %0, %1, %2" : "=v"(r) : "v"(lo), "v"(hic));
        outw[i] = (unsigned int)r;
      }
      *(uint4*)(bB + ((p * 128 + c8i * 16) ^ SWZ(p))) =
          make_uint4(outw[0], outw[1], outw[2], outw[3]);
    }
    __syncthreads();
#pragma unroll
    for (int kk = 0; kk < 2; ++kk) {
      bf16x8 af[4], bfv[4];
      for (int obk = 0; obk < 4; ++obk) {
        int row = wave * 64 + obk * 16 + l15;
        af[obk] = *(const bf16x8*)(aB + ((row * 128 + kk * 64 + q4 * 16) ^ SWZ(row)));
      }
      for (int pb = 0; pb < 4; ++pb) {
        int row = pb * 16 + l15;
        bfv[pb] = *(const bf16x8*)(bB + ((row * 128 + kk * 64 + q4 * 16) ^ SWZ(row)));
      }
      for (int obk = 0; obk < 4; ++obk)
        for (int pb = 0; pb < 4; ++pb)
          acc[obk][pb] = MFMA16(af[obk], bfv[pb], acc[obk][pb], 0, 0, 0);
    }
  }
  for (int obk = 0; obk < 4; ++obk)
    for (int pb = 0; pb < 4; ++pb)
      for (int r = 0; r < 4; ++r) {
        int o = wave * 64 + obk * 16 + q4 * 4 + r;
        int p = p0 + pb * 16 + l15;
        size_t gi = ((size_t)b * NC + o) * HW + p;
        out[gi] = acc[obk][pb][r] + obias[o] + x[gi];
      }
}

// ---------------------------------------------------------------- launch
extern "C" void kernel_launch(void* const* d_in, const int* in_sizes, int n_in,
                              void* d_out, int out_size, void* d_ws, size_t ws_size,
                              hipStream_t stream) {
  (void)in_sizes; (void)n_in; (void)out_size; (void)ws_size;
  const float* x = (const float*)d_in[0];
  const float* gnw = (const float*)d_in[1];
  const float* gnb = (const float*)d_in[2];
  const float* qkvw = (const float*)d_in[3];
  const float* qkvb = (const float*)d_in[4];
  const float* ow = (const float*)d_in[5];
  const float* obias = (const float*)d_in[6];
  float* out = (float*)d_out;

  char* ws = (char*)d_ws;
  float* s_arr = (float*)ws;
  float* t_arr = s_arr + NB * NC;
  size_t tsz = (size_t)NB * HW * NC;  // 8M ushort = 16MB
  unsigned short* qb = (unsigned short*)(ws + 16384);
  unsigned short* kc_ = qb + tsz;
  unsigned short* Oh0 = kc_ + tsz;
  unsigned short* vc = Oh0 + tsz;
  unsigned short* Oh1 = vc + tsz;       // xt aliases this region pre-flash
  unsigned short* xt = Oh1;
  float* Lb = (float*)(Oh1 + tsz);      // 2*NB*HW f32 = 256KB
  unsigned short* wb = (unsigned short*)(Lb + 2 * NB * HW);  // 512KB bf16 W
  unsigned short* owb = wb + 196608;

  hipLaunchKernelGGL(gn_stats_kernel, dim3(NB * 32), dim3(256), 0, stream,
                     x, gnw, gnb, s_arr, t_arr);
  hipLaunchKernelGGL(wconv_kernel, dim3(128), dim3(256), 0, stream,
                     qkvw, ow, wb);
  hipLaunchKernelGGL(gn_apply_kernel, dim3(64, 4, NB), dim3(256), 0, stream,
                     x, s_arr, t_arr, xt);
  hipLaunchKernelGGL(qkv_gemm_kernel, dim3(64, 6, NB), dim3(256), 0, stream,
                     xt, wb, qkvb, qb, kc_, vc);
  hipLaunchKernelGGL(flash_attn_kernel, dim3(512), dim3(256), 0, stream,
                     qb, kc_, vc, Oh0, Oh1, Lb);
  hipLaunchKernelGGL(outproj_kernel, dim3(64, NB), dim3(256), 0, stream,
                     owb, obias, Oh0, Oh1, Lb, x, out);
}